// Round 1
// baseline (774.355 us; speedup 1.0000x reference)
//
#include <hip/hip_runtime.h>
#include <stdint.h>

// Strategy: split-fp32-into-2xbf16 ("3-pass" bf16 MFMA GEMM) for all three GEMM
// stages (QKV projection, QK^T, PV). fp32 has no MFMA on CDNA4; bf16 split gives
// ~fp32 accuracy at ~3x bf16-MFMA cost (~800 TF effective peak vs 157 TF vector).
// Pipeline: split(q,k,v) -> transpose+split(W) -> proj GEMMs (Q,K split out; V
// transposed split out) -> scores GEMM (fp32 out, scale 1/32) -> row softmax
// (P as hi/lo bf16) -> PV GEMM -> d_out fp32.

typedef __attribute__((ext_vector_type(8))) short short8;
typedef __attribute__((ext_vector_type(4))) float f32x4;
typedef __attribute__((ext_vector_type(4))) unsigned short us4;

#define BM 128
#define BN 128
#define BK 32

static __device__ __forceinline__ unsigned short f2bf(float f) {
  unsigned x = __builtin_bit_cast(unsigned, f);
  x += 0x7fffu + ((x >> 16) & 1u);          // round-to-nearest-even
  return (unsigned short)(x >> 16);
}
static __device__ __forceinline__ float bf2f(unsigned short u) {
  return __builtin_bit_cast(float, (unsigned)u << 16);
}

static __device__ __forceinline__ void gload_lds16(void* lds, const void* g) {
  __builtin_amdgcn_global_load_lds(
      (const __attribute__((address_space(1))) unsigned int*)g,
      (__attribute__((address_space(3))) unsigned int*)lds, 16, 0, 0);
}

// ---------------- elementwise hi/lo split ----------------
__global__ void __launch_bounds__(256)
split_hl(const float* __restrict__ x, unsigned short* __restrict__ h,
         unsigned short* __restrict__ l, int n4) {
  int i = blockIdx.x * 256 + threadIdx.x;
  if (i >= n4) return;
  float4 v = ((const float4*)x)[i];
  float vv[4] = {v.x, v.y, v.z, v.w};
  us4 hh, ll;
#pragma unroll
  for (int j = 0; j < 4; ++j) {
    unsigned short hi = f2bf(vv[j]);
    hh[j] = hi;
    ll[j] = f2bf(vv[j] - bf2f(hi));
  }
  *(us4*)(h + (size_t)i * 4) = hh;
  *(us4*)(l + (size_t)i * 4) = ll;
}

// ---------------- W: transpose + split ([K][N] -> [N][K] hi/lo) ----------------
__global__ void __launch_bounds__(256)
wsplit_t(const float* __restrict__ W, unsigned short* __restrict__ th,
         unsigned short* __restrict__ tl, int K, int N) {
  __shared__ float tile[64][65];
  int k0 = blockIdx.y * 64, n0 = blockIdx.x * 64;
  int t = threadIdx.x;
#pragma unroll
  for (int i = 0; i < 16; ++i) {
    int idx = t + i * 256;
    int r = idx >> 6, c = idx & 63;
    tile[r][c] = W[(size_t)(k0 + r) * N + n0 + c];
  }
  __syncthreads();
#pragma unroll
  for (int i = 0; i < 16; ++i) {
    int idx = t + i * 256;
    int nn = idx >> 6, kk = idx & 63;
    float v = tile[kk][nn];
    unsigned short hi = f2bf(v);
    size_t o = (size_t)(n0 + nn) * K + k0 + kk;
    th[o] = hi;
    tl[o] = f2bf(v - bf2f(hi));
  }
}

// ---------------- split-bf16 GEMM: C = scale*(A@B^T) + bias ----------------
// A: [M][K] row-major (hi/lo), B: [N][K] row-major (hi/lo). 3 passes:
// Ah*Bh + Ah*Bl + Al*Bh. MODE 0: fp32 out [M][N]. MODE 1: hi/lo bf16 out.
// MODE 2: hi/lo bf16 out transposed per batch-of-Srows: out[b][n][s].
template <int MODE>
__global__ void __launch_bounds__(256)
gemm_split(const unsigned short* __restrict__ Ah, const unsigned short* __restrict__ Al,
           const unsigned short* __restrict__ Bh, const unsigned short* __restrict__ Bl,
           long sAb, long sBb, int M, int N, int K,
           const float* __restrict__ bias, float scale,
           float* __restrict__ outF, long sOb,
           unsigned short* __restrict__ outH, unsigned short* __restrict__ outL,
           int Srows) {
  __shared__ __align__(16) unsigned short At[BM * BK];  // 8 KB
  __shared__ __align__(16) unsigned short Bt[BN * BK];  // 8 KB
  const int t = threadIdx.x;
  const int wave = t >> 6, lane = t & 63;
  const int wr = (wave >> 1) * 64, wc = (wave & 1) * 64;
  const long zb = blockIdx.z;
  const int m0 = blockIdx.y * BM, n0 = blockIdx.x * BN;
  Ah += zb * sAb; Al += zb * sAb;
  Bh += zb * sBb; Bl += zb * sBb;

  f32x4 acc[4][4] = {};

  const unsigned short* Ap[3] = {Ah, Ah, Al};
  const unsigned short* Bp[3] = {Bh, Bl, Bh};

  const int lrow = lane & 15, lk = lane >> 4;
  const int c0 = wave * 64 + lane;
  char* AtB = (char*)At;
  char* BtB = (char*)Bt;

  for (int p = 0; p < 3; ++p) {
    const unsigned short* Ac = Ap[p];
    const unsigned short* Bc = Bp[p];
    for (int kt = 0; kt < K; kt += BK) {
#pragma unroll
      for (int i = 0; i < 2; ++i) {
        int c = i * 256 + c0;
        // LDS dest is wave-uniform base + lane*16 (HW rule); chunk c -> byte c*16.
        gload_lds16(AtB + (size_t)(i * 256 + wave * 64) * 16,
                    Ac + (size_t)(m0 + (c >> 2)) * K + kt + (c & 3) * 8);
        gload_lds16(BtB + (size_t)(i * 256 + wave * 64) * 16,
                    Bc + (size_t)(n0 + (c >> 2)) * K + kt + (c & 3) * 8);
      }
      __syncthreads();  // drains vmcnt before barrier
      short8 af[4], bfr[4];
#pragma unroll
      for (int m = 0; m < 4; ++m)
        af[m] = *(const short8*)(AtB + (size_t)((wr + m * 16 + lrow) * 64 + lk * 16));
#pragma unroll
      for (int n = 0; n < 4; ++n)
        bfr[n] = *(const short8*)(BtB + (size_t)((wc + n * 16 + lrow) * 64 + lk * 16));
#pragma unroll
      for (int m = 0; m < 4; ++m)
#pragma unroll
        for (int n = 0; n < 4; ++n)
          acc[m][n] = __builtin_amdgcn_mfma_f32_16x16x32_bf16(af[m], bfr[n], acc[m][n], 0, 0, 0);
      __syncthreads();
    }
  }

  // Epilogue. C/D layout: col = lane&15, row = (lane>>4)*4 + r  [m89-verified]
#pragma unroll
  for (int m = 0; m < 4; ++m) {
#pragma unroll
    for (int n = 0; n < 4; ++n) {
      int gcol = n0 + wc + n * 16 + lrow;
      float bv = bias ? bias[gcol] : 0.0f;
#pragma unroll
      for (int r = 0; r < 4; ++r) {
        int grow = m0 + wr + m * 16 + lk * 4 + r;
        float v = acc[m][n][r] * scale + bv;
        if (MODE == 0) {
          outF[zb * sOb + (size_t)grow * N + gcol] = v;
        } else if (MODE == 1) {
          unsigned short hi = f2bf(v);
          size_t o = (size_t)grow * N + gcol;
          outH[o] = hi;
          outL[o] = f2bf(v - bf2f(hi));
        } else {
          int bb = grow / Srows, s = grow - bb * Srows;
          size_t o = (size_t)bb * N * Srows + (size_t)gcol * Srows + s;
          unsigned short hi = f2bf(v);
          outH[o] = hi;
          outL[o] = f2bf(v - bf2f(hi));
        }
      }
    }
  }
}

// ---------------- row softmax: fp32 scores -> hi/lo bf16 P ----------------
__global__ void __launch_bounds__(256)
softmax_rows(const float* __restrict__ sc, unsigned short* __restrict__ ph,
             unsigned short* __restrict__ pl, int S) {
  const size_t row = blockIdx.x;
  const float* sr = sc + row * S;
  int t = threadIdx.x;
  float x[8];
  const float4* s4 = (const float4*)sr;
#pragma unroll
  for (int i = 0; i < 2; ++i) {
    float4 v = s4[t + i * 256];
    x[i * 4 + 0] = v.x; x[i * 4 + 1] = v.y; x[i * 4 + 2] = v.z; x[i * 4 + 3] = v.w;
  }
  float m = x[0];
#pragma unroll
  for (int j = 1; j < 8; ++j) m = fmaxf(m, x[j]);
#pragma unroll
  for (int off = 32; off; off >>= 1) m = fmaxf(m, __shfl_xor(m, off));
  __shared__ float red[4];
  if ((t & 63) == 0) red[t >> 6] = m;
  __syncthreads();
  m = fmaxf(fmaxf(red[0], red[1]), fmaxf(red[2], red[3]));
  float e[8];
  float sum = 0.f;
#pragma unroll
  for (int j = 0; j < 8; ++j) { e[j] = __expf(x[j] - m); sum += e[j]; }
#pragma unroll
  for (int off = 32; off; off >>= 1) sum += __shfl_xor(sum, off);
  __shared__ float red2[4];
  if ((t & 63) == 0) red2[t >> 6] = sum;
  __syncthreads();
  sum = red2[0] + red2[1] + red2[2] + red2[3];
  float rinv = 1.0f / sum;
#pragma unroll
  for (int i = 0; i < 2; ++i) {
    us4 hh, ll;
#pragma unroll
    for (int j = 0; j < 4; ++j) {
      float p = e[i * 4 + j] * rinv;
      unsigned short hi = f2bf(p);
      hh[j] = hi;
      ll[j] = f2bf(p - bf2f(hi));
    }
    size_t o = row * S + (size_t)(t + i * 256) * 4;
    *(us4*)(ph + o) = hh;
    *(us4*)(pl + o) = ll;
  }
}

extern "C" void kernel_launch(void* const* d_in, const int* in_sizes, int n_in,
                              void* d_out, int out_size, void* d_ws, size_t ws_size,
                              hipStream_t stream) {
  const int B = 4, S = 2048, D = 1024, DK = 1024, DV = 1024;
  const float* q = (const float*)d_in[0];
  const float* k = (const float*)d_in[1];
  const float* v = (const float*)d_in[2];
  const float* Wq = (const float*)d_in[3];
  const float* Wk = (const float*)d_in[4];
  const float* Wv = (const float*)d_in[5];
  const float* bq = (const float*)d_in[6];
  const float* bk = (const float*)d_in[7];
  const float* bv = (const float*)d_in[8];

  char* ws = (char*)d_ws;
  const size_t MBy = 1024 * 1024;
  // x-splits: 16 MiB each
  unsigned short* qh = (unsigned short*)(ws + 0 * MBy);
  unsigned short* ql = (unsigned short*)(ws + 16 * MBy);
  unsigned short* kh = (unsigned short*)(ws + 32 * MBy);
  unsigned short* kl = (unsigned short*)(ws + 48 * MBy);
  unsigned short* vh = (unsigned short*)(ws + 64 * MBy);
  unsigned short* vl = (unsigned short*)(ws + 80 * MBy);
  // transposed weight splits: 2 MiB each
  unsigned short* wqth = (unsigned short*)(ws + 96 * MBy);
  unsigned short* wqtl = (unsigned short*)(ws + 98 * MBy);
  unsigned short* wkth = (unsigned short*)(ws + 100 * MBy);
  unsigned short* wktl = (unsigned short*)(ws + 102 * MBy);
  unsigned short* wvth = (unsigned short*)(ws + 104 * MBy);
  unsigned short* wvtl = (unsigned short*)(ws + 106 * MBy);
  // projected Q,K splits: 16 MiB each
  unsigned short* Qh = (unsigned short*)(ws + 108 * MBy);
  unsigned short* Ql = (unsigned short*)(ws + 124 * MBy);
  unsigned short* Kh = (unsigned short*)(ws + 140 * MBy);
  unsigned short* Kl = (unsigned short*)(ws + 156 * MBy);
  // V^T splits: 16 MiB each
  unsigned short* Vth = (unsigned short*)(ws + 172 * MBy);
  unsigned short* Vtl = (unsigned short*)(ws + 188 * MBy);
  // overlays (stream-ordered reuse of dead buffers):
  float* scores = (float*)(ws + 0 * MBy);             // 64 MiB over q/k splits
  unsigned short* Ph = (unsigned short*)(ws + 64 * MBy);   // 32 MiB over v splits
  unsigned short* Pl = (unsigned short*)(ws + 108 * MBy);  // 32 MiB over Q splits
  // peak usage: 204 MiB

  const int n4 = B * S * D / 4;  // 2,097,152
  split_hl<<<n4 / 256, 256, 0, stream>>>(q, qh, ql, n4);
  split_hl<<<n4 / 256, 256, 0, stream>>>(k, kh, kl, n4);
  split_hl<<<n4 / 256, 256, 0, stream>>>(v, vh, vl, n4);

  wsplit_t<<<dim3(DK / 64, D / 64), 256, 0, stream>>>(Wq, wqth, wqtl, D, DK);
  wsplit_t<<<dim3(DK / 64, D / 64), 256, 0, stream>>>(Wk, wkth, wktl, D, DK);
  wsplit_t<<<dim3(DV / 64, D / 64), 256, 0, stream>>>(Wv, wvth, wvtl, D, DV);

  // projections: M = B*S = 8192, N = 1024, K = 1024
  gemm_split<1><<<dim3(DK / BN, (B * S) / BM, 1), 256, 0, stream>>>(
      qh, ql, wqth, wqtl, 0, 0, B * S, DK, D, bq, 1.0f, nullptr, 0, Qh, Ql, S);
  gemm_split<1><<<dim3(DK / BN, (B * S) / BM, 1), 256, 0, stream>>>(
      kh, kl, wkth, wktl, 0, 0, B * S, DK, D, bk, 1.0f, nullptr, 0, Kh, Kl, S);
  gemm_split<2><<<dim3(DV / BN, (B * S) / BM, 1), 256, 0, stream>>>(
      vh, vl, wvth, wvtl, 0, 0, B * S, DV, D, bv, 1.0f, nullptr, 0, Vth, Vtl, S);

  // scores: per batch [S,S] = Q @ K^T * (1/sqrt(1024))
  gemm_split<0><<<dim3(S / BN, S / BM, B), 256, 0, stream>>>(
      Qh, Ql, Kh, Kl, (long)S * DK, (long)S * DK, S, S, DK, nullptr, 0.03125f,
      scores, (long)S * S, nullptr, nullptr, S);

  softmax_rows<<<B * S, 256, 0, stream>>>(scores, Ph, Pl, S);

  // out = P @ V : A = P [S,S], B = V^T [DV,S]
  gemm_split<0><<<dim3(DV / BN, S / BM, B), 256, 0, stream>>>(
      Ph, Pl, Vth, Vtl, (long)S * S, (long)DV * S, S, DV, S, nullptr, 1.0f,
      (float*)d_out, (long)S * DV, nullptr, nullptr, S);
}

// Round 4
// 620.072 us; speedup vs baseline: 1.2488x; 1.2488x over previous
//
#include <hip/hip_runtime.h>
#include <stdint.h>

// Split-fp32-into-2xbf16 ("3-pass") bf16 MFMA GEMM for all three GEMM stages.
// R1 changes vs R0 (resubmitted unchanged in R2/R3 — benches failed on infra):
//  - FUSED passes: stage Ah/Al/Bh/Bl tiles ONCE per K-step (32KB LDS), run all
//    3 MFMA groups (AhBh, AhBl, AlBh) per barrier pair. 3x fewer barriers,
//    2/3 the staging traffic, 48 MFMA per sync instead of 16.
//  - LDS slot swizzle (both-sides: pre-swizzled global source + swizzled read,
//    linear global_load_lds dest) to kill the 8-way granule conflict on
//    ds_read_b128 fragment reads.

typedef __attribute__((ext_vector_type(8))) short short8;
typedef __attribute__((ext_vector_type(4))) float f32x4;
typedef __attribute__((ext_vector_type(4))) unsigned short us4;

#define BM 128
#define BN 128
#define BK 32

static __device__ __forceinline__ unsigned short f2bf(float f) {
  unsigned x = __builtin_bit_cast(unsigned, f);
  x += 0x7fffu + ((x >> 16) & 1u);          // round-to-nearest-even
  return (unsigned short)(x >> 16);
}
static __device__ __forceinline__ float bf2f(unsigned short u) {
  return __builtin_bit_cast(float, (unsigned)u << 16);
}

static __device__ __forceinline__ void gload_lds16(void* lds, const void* g) {
  __builtin_amdgcn_global_load_lds(
      (const __attribute__((address_space(1))) unsigned int*)g,
      (__attribute__((address_space(3))) unsigned int*)lds, 16, 0, 0);
}

// ---------------- elementwise hi/lo split ----------------
__global__ void __launch_bounds__(256)
split_hl(const float* __restrict__ x, unsigned short* __restrict__ h,
         unsigned short* __restrict__ l, int n4) {
  int i = blockIdx.x * 256 + threadIdx.x;
  if (i >= n4) return;
  float4 v = ((const float4*)x)[i];
  float vv[4] = {v.x, v.y, v.z, v.w};
  us4 hh, ll;
#pragma unroll
  for (int j = 0; j < 4; ++j) {
    unsigned short hi = f2bf(vv[j]);
    hh[j] = hi;
    ll[j] = f2bf(vv[j] - bf2f(hi));
  }
  *(us4*)(h + (size_t)i * 4) = hh;
  *(us4*)(l + (size_t)i * 4) = ll;
}

// ---------------- W: transpose + split ([K][N] -> [N][K] hi/lo) ----------------
__global__ void __launch_bounds__(256)
wsplit_t(const float* __restrict__ W, unsigned short* __restrict__ th,
         unsigned short* __restrict__ tl, int K, int N) {
  __shared__ float tile[64][65];
  int k0 = blockIdx.y * 64, n0 = blockIdx.x * 64;
  int t = threadIdx.x;
#pragma unroll
  for (int i = 0; i < 16; ++i) {
    int idx = t + i * 256;
    int r = idx >> 6, c = idx & 63;
    tile[r][c] = W[(size_t)(k0 + r) * N + n0 + c];
  }
  __syncthreads();
#pragma unroll
  for (int i = 0; i < 16; ++i) {
    int idx = t + i * 256;
    int nn = idx >> 6, kk = idx & 63;
    float v = tile[kk][nn];
    unsigned short hi = f2bf(v);
    size_t o = (size_t)(n0 + nn) * K + k0 + kk;
    th[o] = hi;
    tl[o] = f2bf(v - bf2f(hi));
  }
}

// ---------------- fused split-bf16 GEMM: C = scale*(A@B^T) + bias ----------------
// A: [M][K] row-major (hi/lo), B: [N][K] row-major (hi/lo).
// Per K-step: stage Ah,Al,Bh,Bl tiles once; 3 MFMA groups (AhBh + AhBl + AlBh).
// LDS layout swizzle: 16B slot s within a row holds data column-slot
// cs = s ^ ((row>>1)&3). Staged via pre-swizzled GLOBAL source (LDS dest linear,
// per the global_load_lds wave-uniform-dest rule); read side applies same XOR.
// MODE 0: fp32 out [M][N]. MODE 1: hi/lo bf16 out. MODE 2: hi/lo bf16 out
// transposed per batch-of-Srows: out[b][n][s].
template <int MODE>
__global__ void __launch_bounds__(256)
gemm_split(const unsigned short* __restrict__ Ah, const unsigned short* __restrict__ Al,
           const unsigned short* __restrict__ Bh, const unsigned short* __restrict__ Bl,
           long sAb, long sBb, int M, int N, int K,
           const float* __restrict__ bias, float scale,
           float* __restrict__ outF, long sOb,
           unsigned short* __restrict__ outH, unsigned short* __restrict__ outL,
           int Srows) {
  __shared__ __align__(16) unsigned short Lds[4 * BM * BK];  // 32 KB
  const int t = threadIdx.x;
  const int wave = t >> 6, lane = t & 63;
  const int wr = (wave >> 1) * 64, wc = (wave & 1) * 64;
  const long zb = blockIdx.z;
  const int m0 = blockIdx.y * BM, n0 = blockIdx.x * BN;
  Ah += zb * sAb; Al += zb * sAb;
  Bh += zb * sBb; Bl += zb * sBb;

  f32x4 acc[4][4] = {};

  const int lrow = lane & 15, lk = lane >> 4;
  char* AhT = (char*)Lds;
  char* AlT = AhT + 8192;
  char* BhT = AlT + 8192;
  char* BlT = BhT + 8192;

  // read-side swizzle: data column-slot lk lives at physical slot lk ^ sw
  const int sw = (lrow >> 1) & 3;
  const int slotB16 = (lk ^ sw) * 16;

  for (int kt = 0; kt < K; kt += BK) {
#pragma unroll
    for (int i = 0; i < 2; ++i) {
      int c = i * 256 + t;
      int row = c >> 2;
      // physical slot c&3 of row holds data col-slot (c&3)^((row>>1)&3)
      int cs = (c & 3) ^ ((c >> 3) & 3);
      size_t ldsOff = (size_t)(i * 256 + wave * 64) * 16;  // wave-uniform base
      size_t gA = (size_t)(m0 + row) * K + kt + cs * 8;
      size_t gB = (size_t)(n0 + row) * K + kt + cs * 8;
      gload_lds16(AhT + ldsOff, Ah + gA);
      gload_lds16(AlT + ldsOff, Al + gA);
      gload_lds16(BhT + ldsOff, Bh + gB);
      gload_lds16(BlT + ldsOff, Bl + gB);
    }
    __syncthreads();  // compiler drains vmcnt before s_barrier

    const char* Ap[3] = {AhT, AhT, AlT};
    const char* Bp[3] = {BhT, BlT, BhT};
#pragma unroll
    for (int p = 0; p < 3; ++p) {
      short8 af[4], bfr[4];
#pragma unroll
      for (int m = 0; m < 4; ++m)
        af[m] = *(const short8*)(Ap[p] + (size_t)((wr + m * 16 + lrow) * 64) + slotB16);
#pragma unroll
      for (int n = 0; n < 4; ++n)
        bfr[n] = *(const short8*)(Bp[p] + (size_t)((wc + n * 16 + lrow) * 64) + slotB16);
#pragma unroll
      for (int m = 0; m < 4; ++m)
#pragma unroll
        for (int n = 0; n < 4; ++n)
          acc[m][n] = __builtin_amdgcn_mfma_f32_16x16x32_bf16(af[m], bfr[n], acc[m][n], 0, 0, 0);
    }
    __syncthreads();
  }

  // Epilogue. C/D layout: col = lane&15, row = (lane>>4)*4 + r  [m89-verified]
#pragma unroll
  for (int m = 0; m < 4; ++m) {
#pragma unroll
    for (int n = 0; n < 4; ++n) {
      int gcol = n0 + wc + n * 16 + lrow;
      float bv = bias ? bias[gcol] : 0.0f;
#pragma unroll
      for (int r = 0; r < 4; ++r) {
        int grow = m0 + wr + m * 16 + lk * 4 + r;
        float v = acc[m][n][r] * scale + bv;
        if (MODE == 0) {
          outF[zb * sOb + (size_t)grow * N + gcol] = v;
        } else if (MODE == 1) {
          unsigned short hi = f2bf(v);
          size_t o = (size_t)grow * N + gcol;
          outH[o] = hi;
          outL[o] = f2bf(v - bf2f(hi));
        } else {
          int bb = grow / Srows, s = grow - bb * Srows;
          size_t o = (size_t)bb * N * Srows + (size_t)gcol * Srows + s;
          unsigned short hi = f2bf(v);
          outH[o] = hi;
          outL[o] = f2bf(v - bf2f(hi));
        }
      }
    }
  }
}

// ---------------- row softmax: fp32 scores -> hi/lo bf16 P ----------------
__global__ void __launch_bounds__(256)
softmax_rows(const float* __restrict__ sc, unsigned short* __restrict__ ph,
             unsigned short* __restrict__ pl, int S) {
  const size_t row = blockIdx.x;
  const float* sr = sc + row * S;
  int t = threadIdx.x;
  float x[8];
  const float4* s4 = (const float4*)sr;
#pragma unroll
  for (int i = 0; i < 2; ++i) {
    float4 v = s4[t + i * 256];
    x[i * 4 + 0] = v.x; x[i * 4 + 1] = v.y; x[i * 4 + 2] = v.z; x[i * 4 + 3] = v.w;
  }
  float m = x[0];
#pragma unroll
  for (int j = 1; j < 8; ++j) m = fmaxf(m, x[j]);
#pragma unroll
  for (int off = 32; off; off >>= 1) m = fmaxf(m, __shfl_xor(m, off));
  __shared__ float red[4];
  if ((t & 63) == 0) red[t >> 6] = m;
  __syncthreads();
  m = fmaxf(fmaxf(red[0], red[1]), fmaxf(red[2], red[3]));
  float e[8];
  float sum = 0.f;
#pragma unroll
  for (int j = 0; j < 8; ++j) { e[j] = __expf(x[j] - m); sum += e[j]; }
#pragma unroll
  for (int off = 32; off; off >>= 1) sum += __shfl_xor(sum, off);
  __shared__ float red2[4];
  if ((t & 63) == 0) red2[t >> 6] = sum;
  __syncthreads();
  sum = red2[0] + red2[1] + red2[2] + red2[3];
  float rinv = 1.0f / sum;
#pragma unroll
  for (int i = 0; i < 2; ++i) {
    us4 hh, ll;
#pragma unroll
    for (int j = 0; j < 4; ++j) {
      float p = e[i * 4 + j] * rinv;
      unsigned short hi = f2bf(p);
      hh[j] = hi;
      ll[j] = f2bf(p - bf2f(hi));
    }
    size_t o = row * S + (size_t)(t + i * 256) * 4;
    *(us4*)(ph + o) = hh;
    *(us4*)(pl + o) = ll;
  }
}

extern "C" void kernel_launch(void* const* d_in, const int* in_sizes, int n_in,
                              void* d_out, int out_size, void* d_ws, size_t ws_size,
                              hipStream_t stream) {
  const int B = 4, S = 2048, D = 1024, DK = 1024, DV = 1024;
  const float* q = (const float*)d_in[0];
  const float* k = (const float*)d_in[1];
  const float* v = (const float*)d_in[2];
  const float* Wq = (const float*)d_in[3];
  const float* Wk = (const float*)d_in[4];
  const float* Wv = (const float*)d_in[5];
  const float* bq = (const float*)d_in[6];
  const float* bk = (const float*)d_in[7];
  const float* bv = (const float*)d_in[8];

  char* ws = (char*)d_ws;
  const size_t MBy = 1024 * 1024;
  // x-splits: 16 MiB each
  unsigned short* qh = (unsigned short*)(ws + 0 * MBy);
  unsigned short* ql = (unsigned short*)(ws + 16 * MBy);
  unsigned short* kh = (unsigned short*)(ws + 32 * MBy);
  unsigned short* kl = (unsigned short*)(ws + 48 * MBy);
  unsigned short* vh = (unsigned short*)(ws + 64 * MBy);
  unsigned short* vl = (unsigned short*)(ws + 80 * MBy);
  // transposed weight splits: 2 MiB each
  unsigned short* wqth = (unsigned short*)(ws + 96 * MBy);
  unsigned short* wqtl = (unsigned short*)(ws + 98 * MBy);
  unsigned short* wkth = (unsigned short*)(ws + 100 * MBy);
  unsigned short* wktl = (unsigned short*)(ws + 102 * MBy);
  unsigned short* wvth = (unsigned short*)(ws + 104 * MBy);
  unsigned short* wvtl = (unsigned short*)(ws + 106 * MBy);
  // projected Q,K splits: 16 MiB each
  unsigned short* Qh = (unsigned short*)(ws + 108 * MBy);
  unsigned short* Ql = (unsigned short*)(ws + 124 * MBy);
  unsigned short* Kh = (unsigned short*)(ws + 140 * MBy);
  unsigned short* Kl = (unsigned short*)(ws + 156 * MBy);
  // V^T splits: 16 MiB each
  unsigned short* Vth = (unsigned short*)(ws + 172 * MBy);
  unsigned short* Vtl = (unsigned short*)(ws + 188 * MBy);
  // overlays (stream-ordered reuse of dead buffers):
  float* scores = (float*)(ws + 0 * MBy);             // 64 MiB over q/k splits
  unsigned short* Ph = (unsigned short*)(ws + 64 * MBy);   // 32 MiB over v splits
  unsigned short* Pl = (unsigned short*)(ws + 108 * MBy);  // 32 MiB over Q splits
  // peak usage: 204 MiB

  const int n4 = B * S * D / 4;  // 2,097,152
  split_hl<<<n4 / 256, 256, 0, stream>>>(q, qh, ql, n4);
  split_hl<<<n4 / 256, 256, 0, stream>>>(k, kh, kl, n4);
  split_hl<<<n4 / 256, 256, 0, stream>>>(v, vh, vl, n4);

  wsplit_t<<<dim3(DK / 64, D / 64), 256, 0, stream>>>(Wq, wqth, wqtl, D, DK);
  wsplit_t<<<dim3(DK / 64, D / 64), 256, 0, stream>>>(Wk, wkth, wktl, D, DK);
  wsplit_t<<<dim3(DV / 64, D / 64), 256, 0, stream>>>(Wv, wvth, wvtl, D, DV);

  // projections: M = B*S = 8192, N = 1024, K = 1024
  gemm_split<1><<<dim3(DK / BN, (B * S) / BM, 1), 256, 0, stream>>>(
      qh, ql, wqth, wqtl, 0, 0, B * S, DK, D, bq, 1.0f, nullptr, 0, Qh, Ql, S);
  gemm_split<1><<<dim3(DK / BN, (B * S) / BM, 1), 256, 0, stream>>>(
      kh, kl, wkth, wktl, 0, 0, B * S, DK, D, bk, 1.0f, nullptr, 0, Kh, Kl, S);
  gemm_split<2><<<dim3(DV / BN, (B * S) / BM, 1), 256, 0, stream>>>(
      vh, vl, wvth, wvtl, 0, 0, B * S, DV, D, bv, 1.0f, nullptr, 0, Vth, Vtl, S);

  // scores: per batch [S,S] = Q @ K^T * (1/sqrt(1024))
  gemm_split<0><<<dim3(S / BN, S / BM, B), 256, 0, stream>>>(
      Qh, Ql, Kh, Kl, (long)S * DK, (long)S * DK, S, S, DK, nullptr, 0.03125f,
      scores, (long)S * S, nullptr, nullptr, S);

  softmax_rows<<<B * S, 256, 0, stream>>>(scores, Ph, Pl, S);

  // out = P @ V : A = P [S,S], B = V^T [DV,S]
  gemm_split<0><<<dim3(DV / BN, S / BM, B), 256, 0, stream>>>(
      Ph, Pl, Vth, Vtl, (long)S * S, (long)DV * S, S, DV, S, nullptr, 1.0f,
      (float*)d_out, (long)S * DV, nullptr, nullptr, S);
}